// Round 2
// baseline (585.330 us; speedup 1.0000x reference)
//
#include <hip/hip_runtime.h>

#define NN 2048   // atoms
#define CA 128    // c_atom
#define CR 389    // c_ref feature dim
#define CP 16     // c_atom_pair

// ---------------- cl = concat(feats) @ W_feats + b_feats ----------------
// Block: 256 threads = 128 channels x 2 atom-subgroups; 8 atoms per block.
// Features staged in LDS transposed [k][atom] so inner loop reads float4.
__global__ __launch_bounds__(256) void cl_kernel(
    const float* __restrict__ pos, const float* __restrict__ charge,
    const float* __restrict__ mask, const float* __restrict__ elem,
    const float* __restrict__ names, const float* __restrict__ Wf,
    const float* __restrict__ bfeats, float* __restrict__ cl)
{
    __shared__ float ft[CR][8];
    const int tid = threadIdx.x;
    const int n0 = blockIdx.x * 8;

    // Gather concatenated features for 8 atoms: [pos(3),charge(1),mask(1),elem(128),names(256)]
    for (int idx = tid; idx < 8 * CR; idx += 256) {
        int a = idx / CR;             // atom within block
        int k = idx - a * CR;         // feature index (consecutive -> coalesced elem/names)
        int n = n0 + a;
        float v;
        if (k < 3)         v = pos[n * 3 + k];
        else if (k == 3)   v = charge[n];
        else if (k == 4)   v = mask[n];
        else if (k < 133)  v = elem[n * 128 + (k - 5)];
        else               v = names[n * 256 + (k - 133)];
        ft[k][a] = v;
    }
    __syncthreads();

    const int c = tid & 127;
    const int sub = tid >> 7;         // 0/1 -> atoms [0..3] / [4..7]
    float a0 = 0.f, a1 = 0.f, a2 = 0.f, a3 = 0.f;
    for (int k = 0; k < CR; ++k) {
        float w = Wf[k * CA + c];                      // coalesced across c
        float4 f = *(const float4*)&ft[k][sub * 4];    // broadcast within half-wave
        a0 = fmaf(f.x, w, a0);
        a1 = fmaf(f.y, w, a1);
        a2 = fmaf(f.z, w, a2);
        a3 = fmaf(f.w, w, a3);
    }
    const float bb = bfeats[c];
    const int nb = n0 + sub * 4;
    cl[(size_t)(nb + 0) * CA + c] = a0 + bb;
    cl[(size_t)(nb + 1) * CA + c] = a1 + bb;
    cl[(size_t)(nb + 2) * CA + c] = a2 + bb;
    cl[(size_t)(nb + 3) * CA + c] = a3 + bb;
}

// ------- plm[l][m][c] = v * (dlm . Woff[:,c] + inv_sq*Winv[c] + K[c]) -------
// K[c] = Wvm[c] + boff[c] + binv[c] + bvm[c]   (v in {0,1}, v^2 = v)
// One block per l; 256 threads x 8 m-values each. 64B/pair via 4x dwordx4.
__global__ __launch_bounds__(256) void plm_kernel(
    const float* __restrict__ pos, const int* __restrict__ uid,
    const float* __restrict__ Woff, const float* __restrict__ boff,
    const float* __restrict__ Winv, const float* __restrict__ binv,
    const float* __restrict__ Wvm, const float* __restrict__ bvm,
    float* __restrict__ out)
{
    // Per-channel constants (uniform addresses -> scalar loads, L1-resident)
    float w0[CP], w1[CP], w2[CP], wi[CP], kk[CP];
    #pragma unroll
    for (int c = 0; c < CP; ++c) {
        w0[c] = Woff[c];
        w1[c] = Woff[CP + c];
        w2[c] = Woff[2 * CP + c];
        wi[c] = Winv[c];
        kk[c] = Wvm[c] + boff[c] + binv[c] + bvm[c];
    }

    const int l = blockIdx.x;
    const float plx = pos[l * 3 + 0];
    const float ply = pos[l * 3 + 1];
    const float plz = pos[l * 3 + 2];
    const int ul = uid[l];
    const int tid = threadIdx.x;

    for (int j = 0; j < NN / 256; ++j) {
        const int m = j * 256 + tid;
        const float dx = plx - pos[m * 3 + 0];
        const float dy = ply - pos[m * 3 + 1];
        const float dz = plz - pos[m * 3 + 2];
        const float inv = 1.0f / (1.0f + dx * dx + dy * dy + dz * dz);
        const unsigned sel = (uid[m] == ul) ? 0xFFFFFFFFu : 0u;

        alignas(16) float r[CP];
        #pragma unroll
        for (int c = 0; c < CP; ++c)
            r[c] = fmaf(dx, w0[c], fmaf(dy, w1[c], fmaf(dz, w2[c], fmaf(inv, wi[c], kk[c]))));

        // v==0 -> exact +0.0f via bitwise AND (branchless, every element written)
        unsigned* rb = (unsigned*)r;
        #pragma unroll
        for (int c = 0; c < CP; ++c) rb[c] &= sel;

        float4* dst = (float4*)(out + ((size_t)l * NN + m) * CP);
        dst[0] = ((const float4*)r)[0];
        dst[1] = ((const float4*)r)[1];
        dst[2] = ((const float4*)r)[2];
        dst[3] = ((const float4*)r)[3];
    }
}

extern "C" void kernel_launch(void* const* d_in, const int* in_sizes, int n_in,
                              void* d_out, int out_size, void* d_ws, size_t ws_size,
                              hipStream_t stream)
{
    const float* pos    = (const float*)d_in[0];
    const float* charge = (const float*)d_in[1];
    const float* mask   = (const float*)d_in[2];
    const float* elem   = (const float*)d_in[3];
    const float* names  = (const float*)d_in[4];
    const int*   uid    = (const int*)  d_in[5];
    const float* Wf     = (const float*)d_in[6];
    const float* bfeats = (const float*)d_in[7];
    const float* Woff   = (const float*)d_in[8];
    const float* boff   = (const float*)d_in[9];
    const float* Winv   = (const float*)d_in[10];
    const float* binv   = (const float*)d_in[11];
    const float* Wvm    = (const float*)d_in[12];
    const float* bvm    = (const float*)d_in[13];

    float* cl  = (float*)d_out;
    float* plm = (float*)d_out + (size_t)NN * CA;

    cl_kernel<<<NN / 8, 256, 0, stream>>>(pos, charge, mask, elem, names, Wf, bfeats, cl);
    plm_kernel<<<NN, 256, 0, stream>>>(pos, uid, Woff, boff, Winv, binv, Wvm, bvm, plm);
}

// Round 4
// 336.956 us; speedup vs baseline: 1.7371x; 1.7371x over previous
//
#include <hip/hip_runtime.h>

#define NN 2048   // atoms
#define CA 128    // c_atom
#define CR 389    // c_ref feature dim
#define CP 16     // c_atom_pair

typedef float nfloat4 __attribute__((ext_vector_type(4)));  // clang-native: ok for nontemporal builtins

// ---------------- cl = concat(feats) @ W_feats + b_feats ----------------
// 256 blocks x 1024 threads (16 waves/CU). Thread = (atom a = tid>>7, channel
// c = tid&127). Features for 8 atoms staged in LDS; per-wave ft read is a
// broadcast (a uniform within wave); Wf loads coalesced 256 B/wave/instr.
__global__ __launch_bounds__(1024) void cl_kernel(
    const float* __restrict__ pos, const float* __restrict__ charge,
    const float* __restrict__ mask, const float* __restrict__ elem,
    const float* __restrict__ names, const float* __restrict__ Wf,
    const float* __restrict__ bfeats, float* __restrict__ cl)
{
    __shared__ float ft[8][CR];
    const int tid = threadIdx.x;
    const int n0 = blockIdx.x * 8;

    // Gather concatenated features: [pos(3),charge(1),mask(1),elem(128),names(256)]
    for (int idx = tid; idx < 8 * CR; idx += 1024) {
        int a = idx / CR;
        int k = idx - a * CR;          // consecutive k -> coalesced elem/names
        int n = n0 + a;
        float v;
        if (k < 3)         v = pos[n * 3 + k];
        else if (k == 3)   v = charge[n];
        else if (k == 4)   v = mask[n];
        else if (k < 133)  v = elem[n * 128 + (k - 5)];
        else               v = names[n * 256 + (k - 133)];
        ft[a][k] = v;
    }
    __syncthreads();

    const int c = tid & 127;
    const int a = tid >> 7;
    const float* fa = ft[a];
    float acc = 0.f;
    #pragma unroll 8                    // 8 independent Wf loads in flight
    for (int k = 0; k < CR; ++k)
        acc = fmaf(fa[k], Wf[k * CA + c], acc);

    __builtin_nontemporal_store(acc + bfeats[c], &cl[(size_t)(n0 + a) * CA + c]);
}

// ------- plm[l][m][c] = v * (dlm . Woff[:,c] + inv_sq*Winv[c] + K[c]) -------
// K[c] = Wvm[c] + boff[c] + binv[c] + bvm[c]   (v in {0,1}, v^2 = v)
// One block per l. Thread t = (pair slot p = t>>2, channel quad q = t&3):
// each wave's single float4 store covers 64 lanes x 16 B = 1 KB CONTIGUOUS
// (full cache lines -> no read-for-ownership), nontemporal (bypass L2).
__global__ __launch_bounds__(256) void plm_kernel(
    const float* __restrict__ pos, const int* __restrict__ uid,
    const float* __restrict__ Woff, const float* __restrict__ boff,
    const float* __restrict__ Winv, const float* __restrict__ binv,
    const float* __restrict__ Wvm, const float* __restrict__ bvm,
    float* __restrict__ out)
{
    const int tid = threadIdx.x;
    const int q = tid & 3;              // channel quad: channels 4q..4q+3
    const int p = tid >> 2;             // pair slot 0..63

    float w0[4], w1[4], w2[4], wi[4], kk[4];
    #pragma unroll
    for (int i = 0; i < 4; ++i) {
        int c = q * 4 + i;
        w0[i] = Woff[c];
        w1[i] = Woff[CP + c];
        w2[i] = Woff[2 * CP + c];
        wi[i] = Winv[c];
        kk[i] = Wvm[c] + boff[c] + binv[c] + bvm[c];
    }

    const int l = blockIdx.x;
    const float plx = pos[l * 3 + 0];
    const float ply = pos[l * 3 + 1];
    const float plz = pos[l * 3 + 2];
    const int ul = uid[l];
    nfloat4* __restrict__ dst = (nfloat4*)(out + (size_t)l * NN * CP);

    #pragma unroll 4
    for (int j = 0; j < NN / 64; ++j) {   // 32 iterations, 64 pairs each
        const int m = j * 64 + p;
        const float dx = plx - pos[m * 3 + 0];
        const float dy = ply - pos[m * 3 + 1];
        const float dz = plz - pos[m * 3 + 2];
        const float inv = 1.0f / (1.0f + dx * dx + dy * dy + dz * dz);
        const unsigned sel = (uid[m] == ul) ? 0xFFFFFFFFu : 0u;

        float rx = fmaf(dx, w0[0], fmaf(dy, w1[0], fmaf(dz, w2[0], fmaf(inv, wi[0], kk[0]))));
        float ry = fmaf(dx, w0[1], fmaf(dy, w1[1], fmaf(dz, w2[1], fmaf(inv, wi[1], kk[1]))));
        float rz = fmaf(dx, w0[2], fmaf(dy, w1[2], fmaf(dz, w2[2], fmaf(inv, wi[2], kk[2]))));
        float rw = fmaf(dx, w0[3], fmaf(dy, w1[3], fmaf(dz, w2[3], fmaf(inv, wi[3], kk[3]))));

        // v==0 -> exact +0.0f via bitwise AND (branchless, every element written)
        unsigned ux = __float_as_uint(rx) & sel;
        unsigned uy = __float_as_uint(ry) & sel;
        unsigned uz = __float_as_uint(rz) & sel;
        unsigned uw = __float_as_uint(rw) & sel;

        nfloat4 r;
        r.x = __uint_as_float(ux);
        r.y = __uint_as_float(uy);
        r.z = __uint_as_float(uz);
        r.w = __uint_as_float(uw);

        __builtin_nontemporal_store(r, dst + j * 256 + tid);  // 1 KB contiguous/wave
    }
}

extern "C" void kernel_launch(void* const* d_in, const int* in_sizes, int n_in,
                              void* d_out, int out_size, void* d_ws, size_t ws_size,
                              hipStream_t stream)
{
    const float* pos    = (const float*)d_in[0];
    const float* charge = (const float*)d_in[1];
    const float* mask   = (const float*)d_in[2];
    const float* elem   = (const float*)d_in[3];
    const float* names  = (const float*)d_in[4];
    const int*   uid    = (const int*)  d_in[5];
    const float* Wf     = (const float*)d_in[6];
    const float* bfeats = (const float*)d_in[7];
    const float* Woff   = (const float*)d_in[8];
    const float* boff   = (const float*)d_in[9];
    const float* Winv   = (const float*)d_in[10];
    const float* binv   = (const float*)d_in[11];
    const float* Wvm    = (const float*)d_in[12];
    const float* bvm    = (const float*)d_in[13];

    float* cl  = (float*)d_out;
    float* plm = (float*)d_out + (size_t)NN * CA;

    cl_kernel<<<NN / 8, 1024, 0, stream>>>(pos, charge, mask, elem, names, Wf, bfeats, cl);
    plm_kernel<<<NN, 256, 0, stream>>>(pos, uid, Woff, boff, Winv, binv, Wvm, bvm, plm);
}